// Round 7
// baseline (188.987 us; speedup 1.0000x reference)
//
#include <hip/hip_runtime.h>
#include <cmath>
#include <cstdint>
#include <cstring>

// ---------------------------------------------------------------------------
// eps = jax.random.normal(jax.random.key(42), (4,4)) reproduced on HOST.
// (verified PASS in earlier rounds): counter (0,e), XOR-fold the 2x32
// outputs; bits>>9|0x3f800000 -> [1,2); affine to [nextafter(-1,0), 1);
// sqrt(2)*erfinv.
// ---------------------------------------------------------------------------

static inline uint32_t rotl32(uint32_t v, int r) { return (v << r) | (v >> (32 - r)); }

static void threefry2x32_42(uint32_t x0, uint32_t x1, uint32_t& o0, uint32_t& o1) {
    const uint32_t k0 = 0u, k1 = 42u;
    const uint32_t ks[3] = { k0, k1, k0 ^ k1 ^ 0x1BD11BDAu };
    static const int R[8] = { 13, 15, 26, 6, 17, 29, 16, 24 };
    x0 += ks[0];
    x1 += ks[1];
    for (int g = 1; g <= 5; ++g) {
        const int* rr = &R[((g - 1) & 1) * 4];
        for (int j = 0; j < 4; ++j) {
            x0 += x1;
            x1 = rotl32(x1, rr[j]);
            x1 ^= x0;
        }
        x0 += ks[g % 3];
        x1 += ks[(g + 1) % 3] + (uint32_t)g;
    }
    o0 = x0;
    o1 = x1;
}

static double erfinv_d(double x) {
    float xf = (float)x;
    float w = -logf((1.0f - xf) * (1.0f + xf));
    float p;
    if (w < 5.0f) {
        w -= 2.5f;
        p = 2.81022636e-08f;
        p = fmaf(p, w, 3.43273939e-07f);
        p = fmaf(p, w, -3.5233877e-06f);
        p = fmaf(p, w, -4.39150654e-06f);
        p = fmaf(p, w, 0.00021858087f);
        p = fmaf(p, w, -0.00125372503f);
        p = fmaf(p, w, -0.00417768164f);
        p = fmaf(p, w, 0.246640727f);
        p = fmaf(p, w, 1.50140941f);
    } else {
        w = sqrtf(w) - 3.0f;
        p = -0.000200214257f;
        p = fmaf(p, w, 0.000100950558f);
        p = fmaf(p, w, 0.00134934322f);
        p = fmaf(p, w, -0.00367342844f);
        p = fmaf(p, w, 0.00573950773f);
        p = fmaf(p, w, -0.0076224613f);
        p = fmaf(p, w, 0.00943887047f);
        p = fmaf(p, w, 1.00167406f);
        p = fmaf(p, w, 2.83297682f);
    }
    double y = (double)(p * xf);
    const double c = 1.1283791670955126;
    for (int it = 0; it < 3; ++it) {
        double err = erf(y) - x;
        y -= err / (c * exp(-y * y));
    }
    return y;
}

struct EpsT { float e[16]; };

static void compute_eps(float* e) {
    const float lo = -0.99999994f;
    for (int i = 0; i < 16; ++i) {
        uint32_t a, b;
        threefry2x32_42(0u, (uint32_t)i, a, b);
        uint32_t bits = a ^ b;
        uint32_t fb = (bits >> 9) | 0x3f800000u;
        float f;
        memcpy(&f, &fb, 4);
        float u = f - 1.0f;
        float v = u * 2.0f + lo;
        if (v < lo) v = lo;
        e[i] = (float)(sqrt(2.0) * erfinv_d((double)v));
    }
}

// ---------------------------------------------------------------------------
// Shuffle-free MFMA chain via K-permutation (layouts verified end-to-end):
//   C/D: lane (hv=lane>>5, n=lane&31), reg r -> D[row][n], row=(r&3)+8*(r>>2)+4hv
//   A:   lane (hv, m=lane&31), elem j  -> A[m][k=8hv+j]
//   B:   lane (hv, n=lane&31), elem j  -> B[k=8hv+j][n]
// Layers 2/3 relabel K with sigma(16q+8hv+j)=16q+4hv+8*(j>>2)+(j&3) so reg r of
// the previous C/D is exactly elem j=r&7 of B-fragment q=r>>3 (no cross-lane).
// W3 duplicated into output rows 4-7 so both wave halves hold f=0..3 in regs
// 0-3. Mask folds into the W1 A-frag via per-chain SGPR bitmasks.
//
// Round-6 (occupancy, part 2): round-5's diet landed VGPR=64 (8 waves/SIMD
// allowed by HW) but grid=1024 hard-capped residency at 4 blocks/CU =
// 4 waves/SIMD; counters still latency-bound (VALU 40%, MFMA 15.6%, HBM 26%,
// Occ 31.5%). Single-variable change: grid 1024 -> 2048 (8 blocks/CU,
// 4 tiles/wave). Codegen untouched for a clean A/B on the occupancy lever.
// (Round-6 bench was an infra failure — container died; identical resubmit.)
// ---------------------------------------------------------------------------

typedef _Float16 half8 __attribute__((ext_vector_type(8)));
typedef __fp16  fp16x2 __attribute__((ext_vector_type(2)));
typedef __fp16  fp16x4 __attribute__((ext_vector_type(4)));
typedef __fp16  fp16x8 __attribute__((ext_vector_type(8)));
typedef uint32_t uint32x4 __attribute__((ext_vector_type(4)));
typedef float floatx4 __attribute__((ext_vector_type(4)));
typedef float floatx16 __attribute__((ext_vector_type(16)));

// relu + f32->f16 (RTZ, packed) for one 8-wide fragment; pure register code.
static __device__ inline half8 relu_pack8(float a0, float a1, float a2, float a3,
                                          float a4, float a5, float a6, float a7) {
    fp16x2 p0 = __builtin_amdgcn_cvt_pkrtz(fmaxf(a0, 0.f), fmaxf(a1, 0.f));
    fp16x2 p1 = __builtin_amdgcn_cvt_pkrtz(fmaxf(a2, 0.f), fmaxf(a3, 0.f));
    fp16x2 p2 = __builtin_amdgcn_cvt_pkrtz(fmaxf(a4, 0.f), fmaxf(a5, 0.f));
    fp16x2 p3 = __builtin_amdgcn_cvt_pkrtz(fmaxf(a6, 0.f), fmaxf(a7, 0.f));
    fp16x4 q0 = __builtin_shufflevector(p0, p1, 0, 1, 2, 3);
    fp16x4 q1 = __builtin_shufflevector(p2, p3, 0, 1, 2, 3);
    fp16x8 r  = __builtin_shufflevector(q0, q1, 0, 1, 2, 3, 4, 5, 6, 7);
    return __builtin_bit_cast(half8, r);
}

__global__ __launch_bounds__(256, 4) void scm_mfma(
    const float* __restrict__ z,
    const float* __restrict__ W1, const float* __restrict__ b1,
    const float* __restrict__ W2, const float* __restrict__ b2,
    const float* __restrict__ W3, const float* __restrict__ b3,
    const int* __restrict__ mask,
    float* __restrict__ out, EpsT ep, int B)
{
    const int lane = threadIdx.x & 63;
    const int hv   = lane >> 5;          // wave half
    const int n    = lane & 31;          // batch row in tile / m index
    const int wid  = blockIdx.x * (blockDim.x >> 6) + (threadIdx.x >> 6);
    const int nw   = gridDim.x * (blockDim.x >> 6);
    const int T    = B >> 5;             // 32-row tiles

    // ---- mask -> SGPRs (wave-uniform), per-chain f16x2 AND-masks in SGPRs ----
    int mku[16];
#pragma unroll
    for (int t = 0; t < 16; ++t) mku[t] = __builtin_amdgcn_readfirstlane(mask[t]);
    int cond[4];
    uint32_t M01[4], M23[4];             // uniform -> SALU/SGPR
#pragma unroll
    for (int i = 0; i < 4; ++i) {
        cond[i] = mku[i] | mku[4 + i] | mku[8 + i] | mku[12 + i];
        M01[i] = (mku[i]      ? 0x0000FFFFu : 0u) | (mku[4 + i]  ? 0xFFFF0000u : 0u);
        M23[i] = (mku[8 + i]  ? 0x0000FFFFu : 0u) | (mku[12 + i] ? 0xFFFF0000u : 0u);
    }

    // ---- weight fragments (f16), built once per wave ----
    half8 w1, w2f[2], w3f[2];
#pragma unroll
    for (int j = 0; j < 8; ++j)                        // k = 8hv+j, natural
        w1[j] = (_Float16)W1[(hv * 8 + j) * 32 + n];   // W1^T[m=n][k]
    const uint32x4 w1u = __builtin_bit_cast(uint32x4, w1);
#pragma unroll
    for (int q = 0; q < 2; ++q)
#pragma unroll
        for (int j = 0; j < 8; ++j) {
            const int row = 16 * q + 4 * hv + 8 * (j >> 2) + (j & 3);  // sigma(k)
            w2f[q][j] = (_Float16)W2[row * 32 + n];
            w3f[q][j] = (n < 8) ? (_Float16)W3[row * 4 + (n & 3)] : (_Float16)0.f;
        }

    // ---- biases in C/D layout (consumed directly as MFMA C operands) ----
    floatx16 b1v, b2v;
#pragma unroll
    for (int r = 0; r < 16; ++r) {
        const int h = (r & 3) + 8 * (r >> 2) + 4 * hv;
        b1v[r] = b1[h];
        b2v[r] = b2[h];
    }
    // eb[s*4+f] = b3[f] + eps[owned col][f] - b2v[f]; b2v is the L3 C-init
    // (rows >= 8 of that product are never read), so this exactly cancels.
    float eb[8];
#pragma unroll
    for (int s2 = 0; s2 < 2; ++s2)
#pragma unroll
        for (int f = 0; f < 4; ++f)
            eb[s2 * 4 + f] = b3[f] + ep.e[(2 * hv + s2) * 4 + f] - b2v[f];

    // ---- grid-stride tile loop with z prefetch ----
    int t = wid;
    floatx4 za = { 0.f, 0.f, 0.f, 0.f }, zb = za;
    if (t < T) {
        const floatx4* p = reinterpret_cast<const floatx4*>(z + ((size_t)t * 32 + n) * 16) + hv * 2;
        za = p[0]; zb = p[1];                         // z[n][hv*8 .. hv*8+7]
    }
    while (t < T) {
        const int tn = t + nw;
        floatx4 na = { 0.f, 0.f, 0.f, 0.f }, nb = na;
        if (tn < T) {
            const floatx4* p = reinterpret_cast<const floatx4*>(z + ((size_t)tn * 32 + n) * 16) + hv * 2;
            na = p[0]; nb = p[1];
        }

        half8 bz;                                     // Z^T B-frag, k natural (RNE)
        bz[0] = (_Float16)za.x; bz[1] = (_Float16)za.y;
        bz[2] = (_Float16)za.z; bz[3] = (_Float16)za.w;
        bz[4] = (_Float16)zb.x; bz[5] = (_Float16)zb.y;
        bz[6] = (_Float16)zb.z; bz[7] = (_Float16)zb.w;

        float ov[8];                                  // default: f32 passthrough
        ov[0] = za.x; ov[1] = za.y; ov[2] = za.z; ov[3] = za.w;
        ov[4] = zb.x; ov[5] = zb.y; ov[6] = zb.z; ov[7] = zb.w;

#pragma unroll
        for (int i = 0; i < 4; ++i) {
            // per-chain masked W1 A-frag: packed f16 AND with SGPR bitmasks
            uint32x4 wm;
            wm.x = w1u.x & M01[i];
            wm.y = w1u.y & M23[i];
            wm.z = w1u.z & M01[i];
            wm.w = w1u.w & M23[i];
            const half8 w1m = __builtin_bit_cast(half8, wm);
            // L1: K=16, natural order; C = b1v directly
            floatx16 c1 = __builtin_amdgcn_mfma_f32_32x32x16_f16(w1m, bz, b1v, 0, 0, 0);
            half8 pa = relu_pack8(c1[0], c1[1], c1[2], c1[3], c1[4], c1[5], c1[6], c1[7]);
            half8 pb = relu_pack8(c1[8], c1[9], c1[10], c1[11], c1[12], c1[13], c1[14], c1[15]);
            // L2: K=32 via sigma-permuted W2 rows; C = b2v directly
            floatx16 c2 = __builtin_amdgcn_mfma_f32_32x32x16_f16(w2f[0], pa, b2v, 0, 0, 0);
            c2 = __builtin_amdgcn_mfma_f32_32x32x16_f16(w2f[1], pb, c2, 0, 0, 0);
            half8 qa = relu_pack8(c2[0], c2[1], c2[2], c2[3], c2[4], c2[5], c2[6], c2[7]);
            half8 qb = relu_pack8(c2[8], c2[9], c2[10], c2[11], c2[12], c2[13], c2[14], c2[15]);
            // L3: W3 duplicated into rows 4-7; C = b2v (cancelled via eb)
            floatx16 c3 = __builtin_amdgcn_mfma_f32_32x32x16_f16(w3f[0], qa, b2v, 0, 0, 0);
            c3 = __builtin_amdgcn_mfma_f32_32x32x16_f16(w3f[1], qb, c3, 0, 0, 0);

            const int  s2 = i & 1;
            const bool ow = ((i >> 1) == hv);         // this half owns cols 2hv,2hv+1
            const bool wr = ow && (cond[i] != 0);
#pragma unroll
            for (int f = 0; f < 4; ++f) {
                const float vv = c3[f] + eb[s2 * 4 + f];
                ov[s2 * 4 + f] = wr ? vv : ov[s2 * 4 + f];
            }
        }

        // all 64 lanes store: lane (hv,n) writes out[n][8hv .. 8hv+7]
        // nontemporal: pure streaming output, keep L2/L3 for z
        floatx4* op = reinterpret_cast<floatx4*>(out + ((size_t)t * 32 + n) * 16 + hv * 8);
        floatx4 o0 = { ov[0], ov[1], ov[2], ov[3] };
        floatx4 o1 = { ov[4], ov[5], ov[6], ov[7] };
        __builtin_nontemporal_store(o0, op);
        __builtin_nontemporal_store(o1, op + 1);

        t = tn; za = na; zb = nb;
    }
}

extern "C" void kernel_launch(void* const* d_in, const int* in_sizes, int n_in,
                              void* d_out, int out_size, void* d_ws, size_t ws_size,
                              hipStream_t stream) {
    const float* z  = (const float*)d_in[0];
    // d_in[1] = z_int (dead code in reference)
    const float* W1 = (const float*)d_in[2];
    const float* b1 = (const float*)d_in[3];
    const float* W2 = (const float*)d_in[4];
    const float* b2 = (const float*)d_in[5];
    const float* W3 = (const float*)d_in[6];
    const float* b3 = (const float*)d_in[7];
    const int* mask = (const int*)d_in[8];
    // d_in[9] = I (dead code in reference)
    float* out = (float*)d_out;

    const int B = in_sizes[0] / 16;

    EpsT ep;
    compute_eps(ep.e);   // pure host math, deterministic, capture-safe

    // 2048 blocks x 4 waves = 8192 waves; 4 tiles/wave; 8 blocks/CU resident
    // (VGPR=64 -> HW allows 8 waves/SIMD; round-5's grid=1024 capped it at 4)
    dim3 grid(2048), block(256);
    hipLaunchKernelGGL(scm_mfma, grid, block, 0, stream,
                       z, W1, b1, W2, b2, W3, b3, mask, out, ep, B);
}

// Round 8
// 186.699 us; speedup vs baseline: 1.0123x; 1.0123x over previous
//
#include <hip/hip_runtime.h>
#include <cmath>
#include <cstdint>
#include <cstring>

// ---------------------------------------------------------------------------
// eps = jax.random.normal(jax.random.key(42), (4,4)) reproduced on HOST.
// (verified PASS in earlier rounds): counter (0,e), XOR-fold the 2x32
// outputs; bits>>9|0x3f800000 -> [1,2); affine to [nextafter(-1,0), 1);
// sqrt(2)*erfinv.
// ---------------------------------------------------------------------------

static inline uint32_t rotl32(uint32_t v, int r) { return (v << r) | (v >> (32 - r)); }

static void threefry2x32_42(uint32_t x0, uint32_t x1, uint32_t& o0, uint32_t& o1) {
    const uint32_t k0 = 0u, k1 = 42u;
    const uint32_t ks[3] = { k0, k1, k0 ^ k1 ^ 0x1BD11BDAu };
    static const int R[8] = { 13, 15, 26, 6, 17, 29, 16, 24 };
    x0 += ks[0];
    x1 += ks[1];
    for (int g = 1; g <= 5; ++g) {
        const int* rr = &R[((g - 1) & 1) * 4];
        for (int j = 0; j < 4; ++j) {
            x0 += x1;
            x1 = rotl32(x1, rr[j]);
            x1 ^= x0;
        }
        x0 += ks[g % 3];
        x1 += ks[(g + 1) % 3] + (uint32_t)g;
    }
    o0 = x0;
    o1 = x1;
}

static double erfinv_d(double x) {
    float xf = (float)x;
    float w = -logf((1.0f - xf) * (1.0f + xf));
    float p;
    if (w < 5.0f) {
        w -= 2.5f;
        p = 2.81022636e-08f;
        p = fmaf(p, w, 3.43273939e-07f);
        p = fmaf(p, w, -3.5233877e-06f);
        p = fmaf(p, w, -4.39150654e-06f);
        p = fmaf(p, w, 0.00021858087f);
        p = fmaf(p, w, -0.00125372503f);
        p = fmaf(p, w, -0.00417768164f);
        p = fmaf(p, w, 0.246640727f);
        p = fmaf(p, w, 1.50140941f);
    } else {
        w = sqrtf(w) - 3.0f;
        p = -0.000200214257f;
        p = fmaf(p, w, 0.000100950558f);
        p = fmaf(p, w, 0.00134934322f);
        p = fmaf(p, w, -0.00367342844f);
        p = fmaf(p, w, 0.00573950773f);
        p = fmaf(p, w, -0.0076224613f);
        p = fmaf(p, w, 0.00943887047f);
        p = fmaf(p, w, 1.00167406f);
        p = fmaf(p, w, 2.83297682f);
    }
    double y = (double)(p * xf);
    const double c = 1.1283791670955126;
    for (int it = 0; it < 3; ++it) {
        double err = erf(y) - x;
        y -= err / (c * exp(-y * y));
    }
    return y;
}

struct EpsT { float e[16]; };

static void compute_eps(float* e) {
    const float lo = -0.99999994f;
    for (int i = 0; i < 16; ++i) {
        uint32_t a, b;
        threefry2x32_42(0u, (uint32_t)i, a, b);
        uint32_t bits = a ^ b;
        uint32_t fb = (bits >> 9) | 0x3f800000u;
        float f;
        memcpy(&f, &fb, 4);
        float u = f - 1.0f;
        float v = u * 2.0f + lo;
        if (v < lo) v = lo;
        e[i] = (float)(sqrt(2.0) * erfinv_d((double)v));
    }
}

// ---------------------------------------------------------------------------
// Shuffle-free MFMA chain via K-permutation (layouts verified end-to-end):
//   C/D: lane (hv=lane>>5, n=lane&31), reg r -> D[row][n], row=(r&3)+8*(r>>2)+4hv
//   A:   lane (hv, m=lane&31), elem j  -> A[m][k=8hv+j]
//   B:   lane (hv, n=lane&31), elem j  -> B[k=8hv+j][n]
// Layers 2/3 relabel K with sigma(16q+8hv+j)=16q+4hv+8*(j>>2)+(j&3) so reg r of
// the previous C/D is exactly elem j=r&7 of B-fragment q=r>>3 (no cross-lane).
// W3 duplicated into output rows 4-7 so both wave halves hold f=0..3 in regs
// 0-3.
//
// Round-8 (VALU diet at fixed residency): round-7's grid A/B proved occupancy
// is register-capped at 4 waves/SIMD (launch_bounds 128-reg budget), grid
// lever dead. Wall is VALU-issue dominated (~1500 cyc/tile measured). Cuts:
//  * relu AFTER pkrtz via packed v_pk_max_f16 (elementwise_max on fp16x8):
//    identical numerics (max(cvt(x),0) == cvt(max(x,0))), -64 VALU/tile
//  * w1m[4] masked A-frags hoisted to prologue (launch_bounds still forces
//    <=128 total regs, so worst case compiler rematerializes): -16 VALU/tile
//  * grid back to 1024 = exact resident set (measured better than 2048)
// ---------------------------------------------------------------------------

typedef _Float16 half8 __attribute__((ext_vector_type(8)));
typedef __fp16  fp16x2 __attribute__((ext_vector_type(2)));
typedef __fp16  fp16x4 __attribute__((ext_vector_type(4)));
typedef __fp16  fp16x8 __attribute__((ext_vector_type(8)));
typedef uint32_t uint32x4 __attribute__((ext_vector_type(4)));
typedef float floatx4 __attribute__((ext_vector_type(4)));
typedef float floatx16 __attribute__((ext_vector_type(16)));

// f32->f16 (RTZ, packed) then packed relu (v_pk_max_f16); pure register code.
static __device__ inline half8 pack8_relu(float a0, float a1, float a2, float a3,
                                          float a4, float a5, float a6, float a7) {
    fp16x2 p0 = __builtin_amdgcn_cvt_pkrtz(a0, a1);
    fp16x2 p1 = __builtin_amdgcn_cvt_pkrtz(a2, a3);
    fp16x2 p2 = __builtin_amdgcn_cvt_pkrtz(a4, a5);
    fp16x2 p3 = __builtin_amdgcn_cvt_pkrtz(a6, a7);
    fp16x4 q0 = __builtin_shufflevector(p0, p1, 0, 1, 2, 3);
    fp16x4 q1 = __builtin_shufflevector(p2, p3, 0, 1, 2, 3);
    fp16x8 r  = __builtin_shufflevector(q0, q1, 0, 1, 2, 3, 4, 5, 6, 7);
    const fp16x8 z8 = (fp16x8)0;
    r = __builtin_elementwise_max(r, z8);   // 4x v_pk_max_f16
    return __builtin_bit_cast(half8, r);
}

__global__ __launch_bounds__(256, 4) void scm_mfma(
    const float* __restrict__ z,
    const float* __restrict__ W1, const float* __restrict__ b1,
    const float* __restrict__ W2, const float* __restrict__ b2,
    const float* __restrict__ W3, const float* __restrict__ b3,
    const int* __restrict__ mask,
    float* __restrict__ out, EpsT ep, int B)
{
    const int lane = threadIdx.x & 63;
    const int hv   = lane >> 5;          // wave half
    const int n    = lane & 31;          // batch row in tile / m index
    const int wid  = blockIdx.x * (blockDim.x >> 6) + (threadIdx.x >> 6);
    const int nw   = gridDim.x * (blockDim.x >> 6);
    const int T    = B >> 5;             // 32-row tiles

    // ---- mask -> SGPRs (wave-uniform) ----
    int mku[16];
#pragma unroll
    for (int t = 0; t < 16; ++t) mku[t] = __builtin_amdgcn_readfirstlane(mask[t]);
    int cond[4];
    uint32_t M01[4], M23[4];             // uniform -> SALU/SGPR
#pragma unroll
    for (int i = 0; i < 4; ++i) {
        cond[i] = mku[i] | mku[4 + i] | mku[8 + i] | mku[12 + i];
        M01[i] = (mku[i]      ? 0x0000FFFFu : 0u) | (mku[4 + i]  ? 0xFFFF0000u : 0u);
        M23[i] = (mku[8 + i]  ? 0x0000FFFFu : 0u) | (mku[12 + i] ? 0xFFFF0000u : 0u);
    }

    // ---- weight fragments (f16), built once per wave ----
    half8 w1, w2f[2], w3f[2];
#pragma unroll
    for (int j = 0; j < 8; ++j)                        // k = 8hv+j, natural
        w1[j] = (_Float16)W1[(hv * 8 + j) * 32 + n];   // W1^T[m=n][k]
    const uint32x4 w1u = __builtin_bit_cast(uint32x4, w1);
    // all 4 per-chain masked W1 A-frags hoisted out of the tile loop
    half8 w1m[4];
#pragma unroll
    for (int i = 0; i < 4; ++i) {
        uint32x4 wm;
        wm.x = w1u.x & M01[i];
        wm.y = w1u.y & M23[i];
        wm.z = w1u.z & M01[i];
        wm.w = w1u.w & M23[i];
        w1m[i] = __builtin_bit_cast(half8, wm);
    }
#pragma unroll
    for (int q = 0; q < 2; ++q)
#pragma unroll
        for (int j = 0; j < 8; ++j) {
            const int row = 16 * q + 4 * hv + 8 * (j >> 2) + (j & 3);  // sigma(k)
            w2f[q][j] = (_Float16)W2[row * 32 + n];
            w3f[q][j] = (n < 8) ? (_Float16)W3[row * 4 + (n & 3)] : (_Float16)0.f;
        }

    // ---- biases in C/D layout (consumed directly as MFMA C operands) ----
    floatx16 b1v, b2v;
#pragma unroll
    for (int r = 0; r < 16; ++r) {
        const int h = (r & 3) + 8 * (r >> 2) + 4 * hv;
        b1v[r] = b1[h];
        b2v[r] = b2[h];
    }
    // eb[s*4+f] = b3[f] + eps[owned col][f] - b2v[f]; b2v is the L3 C-init
    // (rows >= 8 of that product are never read), so this exactly cancels.
    float eb[8];
#pragma unroll
    for (int s2 = 0; s2 < 2; ++s2)
#pragma unroll
        for (int f = 0; f < 4; ++f)
            eb[s2 * 4 + f] = b3[f] + ep.e[(2 * hv + s2) * 4 + f] - b2v[f];

    // ---- grid-stride tile loop with z prefetch ----
    int t = wid;
    floatx4 za = { 0.f, 0.f, 0.f, 0.f }, zb = za;
    if (t < T) {
        const floatx4* p = reinterpret_cast<const floatx4*>(z + ((size_t)t * 32 + n) * 16) + hv * 2;
        za = p[0]; zb = p[1];                         // z[n][hv*8 .. hv*8+7]
    }
    while (t < T) {
        const int tn = t + nw;
        floatx4 na = { 0.f, 0.f, 0.f, 0.f }, nb = na;
        if (tn < T) {
            const floatx4* p = reinterpret_cast<const floatx4*>(z + ((size_t)tn * 32 + n) * 16) + hv * 2;
            na = p[0]; nb = p[1];
        }

        half8 bz;                                     // Z^T B-frag, k natural (RNE)
        bz[0] = (_Float16)za.x; bz[1] = (_Float16)za.y;
        bz[2] = (_Float16)za.z; bz[3] = (_Float16)za.w;
        bz[4] = (_Float16)zb.x; bz[5] = (_Float16)zb.y;
        bz[6] = (_Float16)zb.z; bz[7] = (_Float16)zb.w;

        float ov[8];                                  // default: f32 passthrough
        ov[0] = za.x; ov[1] = za.y; ov[2] = za.z; ov[3] = za.w;
        ov[4] = zb.x; ov[5] = zb.y; ov[6] = zb.z; ov[7] = zb.w;

#pragma unroll
        for (int i = 0; i < 4; ++i) {
            // L1: K=16, natural order; C = b1v directly
            floatx16 c1 = __builtin_amdgcn_mfma_f32_32x32x16_f16(w1m[i], bz, b1v, 0, 0, 0);
            half8 pa = pack8_relu(c1[0], c1[1], c1[2], c1[3], c1[4], c1[5], c1[6], c1[7]);
            half8 pb = pack8_relu(c1[8], c1[9], c1[10], c1[11], c1[12], c1[13], c1[14], c1[15]);
            // L2: K=32 via sigma-permuted W2 rows; C = b2v directly
            floatx16 c2 = __builtin_amdgcn_mfma_f32_32x32x16_f16(w2f[0], pa, b2v, 0, 0, 0);
            c2 = __builtin_amdgcn_mfma_f32_32x32x16_f16(w2f[1], pb, c2, 0, 0, 0);
            half8 qa = pack8_relu(c2[0], c2[1], c2[2], c2[3], c2[4], c2[5], c2[6], c2[7]);
            half8 qb = pack8_relu(c2[8], c2[9], c2[10], c2[11], c2[12], c2[13], c2[14], c2[15]);
            // L3: W3 duplicated into rows 4-7; C = b2v (cancelled via eb)
            floatx16 c3 = __builtin_amdgcn_mfma_f32_32x32x16_f16(w3f[0], qa, b2v, 0, 0, 0);
            c3 = __builtin_amdgcn_mfma_f32_32x32x16_f16(w3f[1], qb, c3, 0, 0, 0);

            const int  s2 = i & 1;
            const bool ow = ((i >> 1) == hv);         // this half owns cols 2hv,2hv+1
            const bool wr = ow && (cond[i] != 0);
#pragma unroll
            for (int f = 0; f < 4; ++f) {
                const float vv = c3[f] + eb[s2 * 4 + f];
                ov[s2 * 4 + f] = wr ? vv : ov[s2 * 4 + f];
            }
        }

        // all 64 lanes store: lane (hv,n) writes out[n][8hv .. 8hv+7]
        // nontemporal: pure streaming output, keep L2/L3 for z
        floatx4* op = reinterpret_cast<floatx4*>(out + ((size_t)t * 32 + n) * 16 + hv * 8);
        floatx4 o0 = { ov[0], ov[1], ov[2], ov[3] };
        floatx4 o1 = { ov[4], ov[5], ov[6], ov[7] };
        __builtin_nontemporal_store(o0, op);
        __builtin_nontemporal_store(o1, op + 1);

        t = tn; za = na; zb = nb;
    }
}

extern "C" void kernel_launch(void* const* d_in, const int* in_sizes, int n_in,
                              void* d_out, int out_size, void* d_ws, size_t ws_size,
                              hipStream_t stream) {
    const float* z  = (const float*)d_in[0];
    // d_in[1] = z_int (dead code in reference)
    const float* W1 = (const float*)d_in[2];
    const float* b1 = (const float*)d_in[3];
    const float* W2 = (const float*)d_in[4];
    const float* b2 = (const float*)d_in[5];
    const float* W3 = (const float*)d_in[6];
    const float* b3 = (const float*)d_in[7];
    const int* mask = (const int*)d_in[8];
    // d_in[9] = I (dead code in reference)
    float* out = (float*)d_out;

    const int B = in_sizes[0] / 16;

    EpsT ep;
    compute_eps(ep.e);   // pure host math, deterministic, capture-safe

    // 1024 blocks x 4 waves; 8 tiles/wave; 4 blocks/CU = exact resident set
    // (round-7 A/B: residency is register-capped at 4 waves/SIMD; grid 2048
    //  only added prologue/tail cost)
    dim3 grid(1024), block(256);
    hipLaunchKernelGGL(scm_mfma, grid, block, 0, stream,
                       z, W1, b1, W2, b2, W3, b3, mask, out, ep, B);
}

// Round 9
// 184.176 us; speedup vs baseline: 1.0261x; 1.0137x over previous
//
#include <hip/hip_runtime.h>
#include <cmath>
#include <cstdint>
#include <cstring>

// ---------------------------------------------------------------------------
// eps = jax.random.normal(jax.random.key(42), (4,4)) reproduced on HOST.
// (verified PASS in earlier rounds): counter (0,e), XOR-fold the 2x32
// outputs; bits>>9|0x3f800000 -> [1,2); affine to [nextafter(-1,0), 1);
// sqrt(2)*erfinv.
// ---------------------------------------------------------------------------

static inline uint32_t rotl32(uint32_t v, int r) { return (v << r) | (v >> (32 - r)); }

static void threefry2x32_42(uint32_t x0, uint32_t x1, uint32_t& o0, uint32_t& o1) {
    const uint32_t k0 = 0u, k1 = 42u;
    const uint32_t ks[3] = { k0, k1, k0 ^ k1 ^ 0x1BD11BDAu };
    static const int R[8] = { 13, 15, 26, 6, 17, 29, 16, 24 };
    x0 += ks[0];
    x1 += ks[1];
    for (int g = 1; g <= 5; ++g) {
        const int* rr = &R[((g - 1) & 1) * 4];
        for (int j = 0; j < 4; ++j) {
            x0 += x1;
            x1 = rotl32(x1, rr[j]);
            x1 ^= x0;
        }
        x0 += ks[g % 3];
        x1 += ks[(g + 1) % 3] + (uint32_t)g;
    }
    o0 = x0;
    o1 = x1;
}

static double erfinv_d(double x) {
    float xf = (float)x;
    float w = -logf((1.0f - xf) * (1.0f + xf));
    float p;
    if (w < 5.0f) {
        w -= 2.5f;
        p = 2.81022636e-08f;
        p = fmaf(p, w, 3.43273939e-07f);
        p = fmaf(p, w, -3.5233877e-06f);
        p = fmaf(p, w, -4.39150654e-06f);
        p = fmaf(p, w, 0.00021858087f);
        p = fmaf(p, w, -0.00125372503f);
        p = fmaf(p, w, -0.00417768164f);
        p = fmaf(p, w, 0.246640727f);
        p = fmaf(p, w, 1.50140941f);
    } else {
        w = sqrtf(w) - 3.0f;
        p = -0.000200214257f;
        p = fmaf(p, w, 0.000100950558f);
        p = fmaf(p, w, 0.00134934322f);
        p = fmaf(p, w, -0.00367342844f);
        p = fmaf(p, w, 0.00573950773f);
        p = fmaf(p, w, -0.0076224613f);
        p = fmaf(p, w, 0.00943887047f);
        p = fmaf(p, w, 1.00167406f);
        p = fmaf(p, w, 2.83297682f);
    }
    double y = (double)(p * xf);
    const double c = 1.1283791670955126;
    for (int it = 0; it < 3; ++it) {
        double err = erf(y) - x;
        y -= err / (c * exp(-y * y));
    }
    return y;
}

struct EpsT { float e[16]; };

static void compute_eps(float* e) {
    const float lo = -0.99999994f;
    for (int i = 0; i < 16; ++i) {
        uint32_t a, b;
        threefry2x32_42(0u, (uint32_t)i, a, b);
        uint32_t bits = a ^ b;
        uint32_t fb = (bits >> 9) | 0x3f800000u;
        float f;
        memcpy(&f, &fb, 4);
        float u = f - 1.0f;
        float v = u * 2.0f + lo;
        if (v < lo) v = lo;
        e[i] = (float)(sqrt(2.0) * erfinv_d((double)v));
    }
}

// ---------------------------------------------------------------------------
// Shuffle-free MFMA chain via K-permutation (layouts verified end-to-end):
//   C/D: lane (hv=lane>>5, n=lane&31), reg r -> D[row][n], row=(r&3)+8*(r>>2)+4hv
//   A:   lane (hv, m=lane&31), elem j  -> A[m][k=8hv+j]
//   B:   lane (hv, n=lane&31), elem j  -> B[k=8hv+j][n]
// Layers 2/3 relabel K with sigma(16q+8hv+j)=16q+4hv+8*(j>>2)+(j&3) so reg r of
// the previous C/D is exactly elem j=r&7 of B-fragment q=r>>3 (no cross-lane).
// W3 duplicated into output rows 4-7 so both wave halves hold f=0..3 in regs
// 0-3.
//
// Round-9 (latency attack): round-8 proved no pipe is the wall (VALU 22%,
// MFMA 16%, HBM 29%) — per-wave per-tile wall ~925cy matches the 4 column-
// chains executing SERIALLY (~220cy dep-chain each). At launch_bounds(256,4)
// the 128-reg unified budget can't hold 2 chains' live state, so the
// scheduler serializes. Trade: 1 wave for 2x ILP.
//  * __launch_bounds__(256,3): ~170-reg budget -> 2 chains can be live
//  * chains interleaved PAIRWISE in source ((0,1) then (2,3)): both L1
//    MFMAs, then both packs, then both L2 pairs, etc.
//  * grid 768 = exact 3 blocks/CU resident
//  * plain stores (round-8 counters: nontemporal RAISED write traffic
//    65->77MB and fetch +2MB for no gain)
// ---------------------------------------------------------------------------

typedef _Float16 half8 __attribute__((ext_vector_type(8)));
typedef __fp16  fp16x2 __attribute__((ext_vector_type(2)));
typedef __fp16  fp16x4 __attribute__((ext_vector_type(4)));
typedef __fp16  fp16x8 __attribute__((ext_vector_type(8)));
typedef uint32_t uint32x4 __attribute__((ext_vector_type(4)));
typedef float floatx4 __attribute__((ext_vector_type(4)));
typedef float floatx16 __attribute__((ext_vector_type(16)));

// f32->f16 (RTZ, packed) then packed relu (v_pk_max_f16); pure register code.
static __device__ inline half8 pack8_relu(float a0, float a1, float a2, float a3,
                                          float a4, float a5, float a6, float a7) {
    fp16x2 p0 = __builtin_amdgcn_cvt_pkrtz(a0, a1);
    fp16x2 p1 = __builtin_amdgcn_cvt_pkrtz(a2, a3);
    fp16x2 p2 = __builtin_amdgcn_cvt_pkrtz(a4, a5);
    fp16x2 p3 = __builtin_amdgcn_cvt_pkrtz(a6, a7);
    fp16x4 q0 = __builtin_shufflevector(p0, p1, 0, 1, 2, 3);
    fp16x4 q1 = __builtin_shufflevector(p2, p3, 0, 1, 2, 3);
    fp16x8 r  = __builtin_shufflevector(q0, q1, 0, 1, 2, 3, 4, 5, 6, 7);
    const fp16x8 z8 = (fp16x8)0;
    r = __builtin_elementwise_max(r, z8);   // 4x v_pk_max_f16
    return __builtin_bit_cast(half8, r);
}

__global__ __launch_bounds__(256, 3) void scm_mfma(
    const float* __restrict__ z,
    const float* __restrict__ W1, const float* __restrict__ b1,
    const float* __restrict__ W2, const float* __restrict__ b2,
    const float* __restrict__ W3, const float* __restrict__ b3,
    const int* __restrict__ mask,
    float* __restrict__ out, EpsT ep, int B)
{
    const int lane = threadIdx.x & 63;
    const int hv   = lane >> 5;          // wave half
    const int n    = lane & 31;          // batch row in tile / m index
    const int wid  = blockIdx.x * (blockDim.x >> 6) + (threadIdx.x >> 6);
    const int nw   = gridDim.x * (blockDim.x >> 6);
    const int T    = B >> 5;             // 32-row tiles

    // ---- mask -> SGPRs (wave-uniform) ----
    int mku[16];
#pragma unroll
    for (int t = 0; t < 16; ++t) mku[t] = __builtin_amdgcn_readfirstlane(mask[t]);
    int cond[4];
    uint32_t M01[4], M23[4];             // uniform -> SALU/SGPR
#pragma unroll
    for (int i = 0; i < 4; ++i) {
        cond[i] = mku[i] | mku[4 + i] | mku[8 + i] | mku[12 + i];
        M01[i] = (mku[i]      ? 0x0000FFFFu : 0u) | (mku[4 + i]  ? 0xFFFF0000u : 0u);
        M23[i] = (mku[8 + i]  ? 0x0000FFFFu : 0u) | (mku[12 + i] ? 0xFFFF0000u : 0u);
    }

    // ---- weight fragments (f16), built once per wave ----
    half8 w1, w2f[2], w3f[2];
#pragma unroll
    for (int j = 0; j < 8; ++j)                        // k = 8hv+j, natural
        w1[j] = (_Float16)W1[(hv * 8 + j) * 32 + n];   // W1^T[m=n][k]
    const uint32x4 w1u = __builtin_bit_cast(uint32x4, w1);
    // all 4 per-chain masked W1 A-frags hoisted out of the tile loop
    half8 w1m[4];
#pragma unroll
    for (int i = 0; i < 4; ++i) {
        uint32x4 wm;
        wm.x = w1u.x & M01[i];
        wm.y = w1u.y & M23[i];
        wm.z = w1u.z & M01[i];
        wm.w = w1u.w & M23[i];
        w1m[i] = __builtin_bit_cast(half8, wm);
    }
#pragma unroll
    for (int q = 0; q < 2; ++q)
#pragma unroll
        for (int j = 0; j < 8; ++j) {
            const int row = 16 * q + 4 * hv + 8 * (j >> 2) + (j & 3);  // sigma(k)
            w2f[q][j] = (_Float16)W2[row * 32 + n];
            w3f[q][j] = (n < 8) ? (_Float16)W3[row * 4 + (n & 3)] : (_Float16)0.f;
        }

    // ---- biases in C/D layout (consumed directly as MFMA C operands) ----
    floatx16 b1v, b2v;
#pragma unroll
    for (int r = 0; r < 16; ++r) {
        const int h = (r & 3) + 8 * (r >> 2) + 4 * hv;
        b1v[r] = b1[h];
        b2v[r] = b2[h];
    }
    // eb[s*4+f] = b3[f] + eps[owned col][f] - b2v[f]; b2v is the L3 C-init
    // (rows >= 8 of that product are never read), so this exactly cancels.
    float eb[8];
#pragma unroll
    for (int s2 = 0; s2 < 2; ++s2)
#pragma unroll
        for (int f = 0; f < 4; ++f)
            eb[s2 * 4 + f] = b3[f] + ep.e[(2 * hv + s2) * 4 + f] - b2v[f];

    // ---- grid-stride tile loop with z prefetch ----
    int t = wid;
    floatx4 za = { 0.f, 0.f, 0.f, 0.f }, zb = za;
    if (t < T) {
        const floatx4* p = reinterpret_cast<const floatx4*>(z + ((size_t)t * 32 + n) * 16) + hv * 2;
        za = p[0]; zb = p[1];                         // z[n][hv*8 .. hv*8+7]
    }
    while (t < T) {
        const int tn = t + nw;
        floatx4 na = { 0.f, 0.f, 0.f, 0.f }, nb = na;
        if (tn < T) {
            const floatx4* p = reinterpret_cast<const floatx4*>(z + ((size_t)tn * 32 + n) * 16) + hv * 2;
            na = p[0]; nb = p[1];
        }

        half8 bz;                                     // Z^T B-frag, k natural (RNE)
        bz[0] = (_Float16)za.x; bz[1] = (_Float16)za.y;
        bz[2] = (_Float16)za.z; bz[3] = (_Float16)za.w;
        bz[4] = (_Float16)zb.x; bz[5] = (_Float16)zb.y;
        bz[6] = (_Float16)zb.z; bz[7] = (_Float16)zb.w;

        float ov[8];                                  // default: f32 passthrough
        ov[0] = za.x; ov[1] = za.y; ov[2] = za.z; ov[3] = za.w;
        ov[4] = zb.x; ov[5] = zb.y; ov[6] = zb.z; ov[7] = zb.w;

        // two PAIRS of interleaved column-chains: (0,1) then (2,3).
        // Within a pair, both chains' MFMAs are issued back-to-back at each
        // stage so the scheduler can hide each chain's latency in the other.
#pragma unroll
        for (int p2 = 0; p2 < 2; ++p2) {
            const int iA = 2 * p2, iB = 2 * p2 + 1;
            // L1 x2
            floatx16 cA = __builtin_amdgcn_mfma_f32_32x32x16_f16(w1m[iA], bz, b1v, 0, 0, 0);
            floatx16 cB = __builtin_amdgcn_mfma_f32_32x32x16_f16(w1m[iB], bz, b1v, 0, 0, 0);
            half8 paA = pack8_relu(cA[0], cA[1], cA[2], cA[3], cA[4], cA[5], cA[6], cA[7]);
            half8 pbA = pack8_relu(cA[8], cA[9], cA[10], cA[11], cA[12], cA[13], cA[14], cA[15]);
            half8 paB = pack8_relu(cB[0], cB[1], cB[2], cB[3], cB[4], cB[5], cB[6], cB[7]);
            half8 pbB = pack8_relu(cB[8], cB[9], cB[10], cB[11], cB[12], cB[13], cB[14], cB[15]);
            // L2 x2 (sigma-permuted W2 rows; C = b2v directly)
            floatx16 dA = __builtin_amdgcn_mfma_f32_32x32x16_f16(w2f[0], paA, b2v, 0, 0, 0);
            floatx16 dB = __builtin_amdgcn_mfma_f32_32x32x16_f16(w2f[0], paB, b2v, 0, 0, 0);
            dA = __builtin_amdgcn_mfma_f32_32x32x16_f16(w2f[1], pbA, dA, 0, 0, 0);
            dB = __builtin_amdgcn_mfma_f32_32x32x16_f16(w2f[1], pbB, dB, 0, 0, 0);
            half8 qaA = pack8_relu(dA[0], dA[1], dA[2], dA[3], dA[4], dA[5], dA[6], dA[7]);
            half8 qbA = pack8_relu(dA[8], dA[9], dA[10], dA[11], dA[12], dA[13], dA[14], dA[15]);
            half8 qaB = pack8_relu(dB[0], dB[1], dB[2], dB[3], dB[4], dB[5], dB[6], dB[7]);
            half8 qbB = pack8_relu(dB[8], dB[9], dB[10], dB[11], dB[12], dB[13], dB[14], dB[15]);
            // L3 x2 (W3 duplicated into rows 4-7; C = b2v cancelled via eb)
            floatx16 eA = __builtin_amdgcn_mfma_f32_32x32x16_f16(w3f[0], qaA, b2v, 0, 0, 0);
            floatx16 eB = __builtin_amdgcn_mfma_f32_32x32x16_f16(w3f[0], qaB, b2v, 0, 0, 0);
            eA = __builtin_amdgcn_mfma_f32_32x32x16_f16(w3f[1], qbA, eA, 0, 0, 0);
            eB = __builtin_amdgcn_mfma_f32_32x32x16_f16(w3f[1], qbB, eB, 0, 0, 0);

            // chain iA -> ov[0..3] (s2=0), chain iB -> ov[4..7] (s2=1),
            // both only if this half owns the pair (p2 == hv) and cond set.
            const bool ow  = (p2 == hv);
            const bool wrA = ow && (cond[iA] != 0);
            const bool wrB = ow && (cond[iB] != 0);
#pragma unroll
            for (int f = 0; f < 4; ++f) {
                const float vA = eA[f] + eb[f];
                const float vB = eB[f] + eb[4 + f];
                ov[f]     = wrA ? vA : ov[f];
                ov[4 + f] = wrB ? vB : ov[4 + f];
            }
        }

        // all 64 lanes store: lane (hv,n) writes out[n][8hv .. 8hv+7]
        floatx4* op = reinterpret_cast<floatx4*>(out + ((size_t)t * 32 + n) * 16 + hv * 8);
        floatx4 o0 = { ov[0], ov[1], ov[2], ov[3] };
        floatx4 o1 = { ov[4], ov[5], ov[6], ov[7] };
        op[0] = o0;
        op[1] = o1;

        t = tn; za = na; zb = nb;
    }
}

extern "C" void kernel_launch(void* const* d_in, const int* in_sizes, int n_in,
                              void* d_out, int out_size, void* d_ws, size_t ws_size,
                              hipStream_t stream) {
    const float* z  = (const float*)d_in[0];
    // d_in[1] = z_int (dead code in reference)
    const float* W1 = (const float*)d_in[2];
    const float* b1 = (const float*)d_in[3];
    const float* W2 = (const float*)d_in[4];
    const float* b2 = (const float*)d_in[5];
    const float* W3 = (const float*)d_in[6];
    const float* b3 = (const float*)d_in[7];
    const int* mask = (const int*)d_in[8];
    // d_in[9] = I (dead code in reference)
    float* out = (float*)d_out;

    const int B = in_sizes[0] / 16;

    EpsT ep;
    compute_eps(ep.e);   // pure host math, deterministic, capture-safe

    // 768 blocks x 4 waves; 3 blocks/CU = exact resident set at 3 waves/SIMD
    dim3 grid(768), block(256);
    hipLaunchKernelGGL(scm_mfma, grid, block, 0, stream,
                       z, W1, b1, W2, b2, W3, b3, mask, out, ep, B);
}